// Round 1
// baseline (4840.534 us; speedup 1.0000x reference)
//
#include <hip/hip_runtime.h>

#define CAP 128   // padded-ELL row capacity; max degree ~60 for Poisson(32)

typedef __bf16 bf16x8 __attribute__((ext_vector_type(8)));
typedef float  f32x4  __attribute__((ext_vector_type(4)));

__device__ __forceinline__ unsigned short f2bf(float f) {
  // round-to-nearest-even float -> bf16 (inputs are finite)
  unsigned int u = __float_as_uint(f);
  unsigned int r = (u + 0x7FFFu + ((u >> 16) & 1u)) >> 16;
  return (unsigned short)r;
}

// ---------------- weight transpose + cast:  W[K][Nv] f32 -> Wt[Nv][Kp] bf16 (zero-padded K) ----
__global__ __launch_bounds__(256)
void transpose_cast(const float* __restrict__ W, unsigned short* __restrict__ Wt,
                    int K, int Nv, int Kp) {
  __shared__ float tile[32][33];
  int kb = blockIdx.x * 32, nb = blockIdx.y * 32;
  int tx = threadIdx.x, ty = threadIdx.y;   // 32 x 8
  for (int i = ty; i < 32; i += 8) {
    int k = kb + i, n = nb + tx;
    tile[i][tx] = (k < K && n < Nv) ? W[(size_t)k * Nv + n] : 0.f;
  }
  __syncthreads();
  for (int i = ty; i < 32; i += 8) {
    int n = nb + i, k = kb + tx;
    if (n < Nv && k < Kp) Wt[(size_t)n * Kp + k] = f2bf(tile[tx][i]);
  }
}

// ---------------- padded-ELL build ----------------
__global__ __launch_bounds__(256)
void ell_build(const int* __restrict__ erows, const int* __restrict__ ecols,
               const float* __restrict__ evals, int* __restrict__ cnt,
               int* __restrict__ ec, float* __restrict__ ev, int E) {
  int e = blockIdx.x * 256 + threadIdx.x;
  if (e >= E) return;
  int r = erows[e];
  int slot = atomicAdd(&cnt[r], 1);
  if (slot < CAP) {
    ec[(size_t)r * CAP + slot] = ecols[e];
    ev[(size_t)r * CAP + slot] = evals[e];
  }
}

// ---------------- SpMM over padded ELL: out[r][:] = sum_j val_j * S[col_j][:]  (+bias,relu) ----
template<bool RELU, bool BIAS>
__global__ __launch_bounds__(256)
void spmm_kernel(const float* __restrict__ S, const int* __restrict__ cnt,
                 const int* __restrict__ ec, const float* __restrict__ ev,
                 const float* __restrict__ bias, float* __restrict__ out, int nv /*dim/4*/) {
  int r = blockIdx.x;
  int t = threadIdx.x;
  if (t >= nv) return;
  int c = cnt[r]; if (c > CAP) c = CAP;
  const float4* S4 = (const float4*)S;
  float4 acc = make_float4(0.f, 0.f, 0.f, 0.f);
  size_t base = (size_t)r * CAP;
  for (int j = 0; j < c; ++j) {
    int col = ec[base + j];
    float v  = ev[base + j];
    float4 s = S4[(size_t)col * nv + t];
    acc.x += v * s.x; acc.y += v * s.y; acc.z += v * s.z; acc.w += v * s.w;
  }
  if (BIAS) {
    float4 bb = ((const float4*)bias)[t];
    acc.x += bb.x; acc.y += bb.y; acc.z += bb.z; acc.w += bb.w;
  }
  if (RELU) {
    acc.x = fmaxf(acc.x, 0.f); acc.y = fmaxf(acc.y, 0.f);
    acc.z = fmaxf(acc.z, 0.f); acc.w = fmaxf(acc.w, 0.f);
  }
  ((float4*)out)[(size_t)r * nv + t] = acc;
}

// ---------------- GEMM: C[M][Nv] = A[M][K] (f32, cast to bf16 in staging) @ Wt[Nv][Kp]^T ------
// 128x128 tile, BK=32, 4 waves of 64x64 = 4x4 mfma_f32_16x16x32_bf16 fragments.
template<bool RELU, bool BIAS>
__global__ __launch_bounds__(256)
void gemm_kernel(const float* __restrict__ A, const unsigned short* __restrict__ Bt,
                 const float* __restrict__ bias, float* __restrict__ C,
                 int M, int K, int Kp, int Nv) {
  __shared__ unsigned short As[128][40];   // +8 pad: 2-way-max bank aliasing on ds_read_b128
  __shared__ unsigned short Bs[128][40];

  int m0 = blockIdx.x * 128, n0 = blockIdx.y * 128;
  int t = threadIdx.x;
  int w = t >> 6, l = t & 63;
  int wr = (w >> 1) * 64, wc = (w & 1) * 64;
  int lr = l & 15, lk = (l >> 4) * 8;

  f32x4 acc[4][4] = {};

  int srow = t >> 1;              // staging: 128 rows, 2 threads/row
  int skg  = (t & 1) * 16;        // each thread stages 16 elements of K

  int nk = (K + 31) / 32;
  for (int kt = 0; kt < nk; ++kt) {
    int k0 = kt * 32;
    { // stage A (f32 -> bf16)
      int gm = m0 + srow;
      unsigned short* dst = &As[srow][skg];
      const float* src = A + (size_t)gm * K + k0 + skg;
      if (gm < M && (K & 3) == 0 && k0 + skg + 16 <= K) {
        #pragma unroll
        for (int j = 0; j < 4; ++j) {
          float4 v = reinterpret_cast<const float4*>(src)[j];
          unsigned int lo = (unsigned int)f2bf(v.x) | ((unsigned int)f2bf(v.y) << 16);
          unsigned int hi = (unsigned int)f2bf(v.z) | ((unsigned int)f2bf(v.w) << 16);
          reinterpret_cast<uint2*>(dst)[j] = make_uint2(lo, hi);
        }
      } else {
        for (int j = 0; j < 16; ++j) {
          int k = k0 + skg + j;
          float v = (gm < M && k < K) ? A[(size_t)gm * K + k] : 0.f;
          dst[j] = f2bf(v);
        }
      }
    }
    { // stage B (bf16 copy from padded Wt)
      int gn = n0 + srow;
      unsigned short* dst = &Bs[srow][skg];
      if (gn < Nv && k0 + skg + 16 <= Kp) {
        const uint4* src = reinterpret_cast<const uint4*>(Bt + (size_t)gn * Kp + k0 + skg);
        reinterpret_cast<uint4*>(dst)[0] = src[0];
        reinterpret_cast<uint4*>(dst)[1] = src[1];
      } else {
        for (int j = 0; j < 16; ++j) {
          int k = k0 + skg + j;
          dst[j] = (gn < Nv && k < Kp) ? Bt[(size_t)gn * Kp + k] : (unsigned short)0;
        }
      }
    }
    __syncthreads();

    bf16x8 a[4], b[4];
    #pragma unroll
    for (int i = 0; i < 4; ++i)
      a[i] = *reinterpret_cast<const bf16x8*>(&As[wr + i * 16 + lr][lk]);
    #pragma unroll
    for (int j = 0; j < 4; ++j)
      b[j] = *reinterpret_cast<const bf16x8*>(&Bs[wc + j * 16 + lr][lk]);
    #pragma unroll
    for (int i = 0; i < 4; ++i)
      #pragma unroll
      for (int j = 0; j < 4; ++j)
        acc[i][j] = __builtin_amdgcn_mfma_f32_16x16x32_bf16(a[i], b[j], acc[i][j], 0, 0, 0);
    __syncthreads();
  }

  // epilogue: C/D layout col=lane&15, row=(lane>>4)*4+reg  [m89-verified]
  int cr = (l >> 4) * 4, cc = l & 15;
  #pragma unroll
  for (int i = 0; i < 4; ++i) {
    #pragma unroll
    for (int j = 0; j < 4; ++j) {
      int gcol = n0 + wc + j * 16 + cc;
      if (gcol >= Nv) continue;
      float bv = BIAS ? bias[gcol] : 0.f;
      #pragma unroll
      for (int q = 0; q < 4; ++q) {
        int grow = m0 + wr + i * 16 + cr + q;
        if (grow >= M) continue;
        float v = acc[i][j][q] + bv;
        if (RELU) v = fmaxf(v, 0.f);
        C[(size_t)grow * Nv + gcol] = v;
      }
    }
  }
}

// ------------------------------------------------------------------------------------
extern "C" void kernel_launch(void* const* d_in, const int* in_sizes, int n_in,
                              void* d_out, int out_size, void* d_ws, size_t ws_size,
                              hipStream_t stream) {
  const float* x        = (const float*)d_in[0];
  const int*   erows    = (const int*)d_in[1];
  const int*   ecols_in = (const int*)d_in[2];
  const float* evals_in = (const float*)d_in[3];
  const float* w[8]; const float* bia[8];
  for (int i = 0; i < 8; ++i) { w[i] = (const float*)d_in[4 + 2 * i]; bia[i] = (const float*)d_in[5 + 2 * i]; }

  const int IN_DIM = 3703;
  const int M = in_sizes[0] / IN_DIM;       // 20000
  const int E = in_sizes[1];                // 640000
  // layer i: GEMM K -> Nv   (0-3 encoder, 4-7 decoder)
  const int Kd[8] = {3703, 1024, 512, 256,   16, 256, 512, 1024};
  const int Nd[8] = {1024,  512, 256,  16,  256, 512, 1024, 3703};
  int Kp[8]; for (int i = 0; i < 8; ++i) Kp[i] = (Kd[i] + 15) & ~15;

  // workspace carve
  char* p = (char*)d_ws;
  auto alloc = [&](size_t bytes) { char* r = p; p += (bytes + 255) & ~(size_t)255; return r; };
  unsigned short* Wt[8];
  for (int i = 0; i < 8; ++i) Wt[i] = (unsigned short*)alloc((size_t)Nd[i] * Kp[i] * 2);
  int*   cnt = (int*)alloc((size_t)M * 4);
  int*   ec  = (int*)alloc((size_t)M * CAP * 4);
  float* ev  = (float*)alloc((size_t)M * CAP * 4);
  float* P   = (float*)alloc((size_t)M * 1024 * 4);

  float* Z  = (float*)d_out;                // z region: M x 16
  float* Q  = (float*)d_out + (size_t)M * 16;  // activation ping buffer aliases x_recon region
  float* XR = Q;                            // x_recon written last, after Q's final read

  // prep: adjacency + weights
  hipMemsetAsync(cnt, 0, (size_t)M * 4, stream);
  ell_build<<<(E + 255) / 256, 256, 0, stream>>>(erows, ecols_in, evals_in, cnt, ec, ev, E);
  for (int i = 0; i < 8; ++i) {
    dim3 g((Kp[i] + 31) / 32, (Nd[i] + 31) / 32);
    transpose_cast<<<g, dim3(32, 8), 0, stream>>>(w[i], Wt[i], Kd[i], Nd[i], Kp[i]);
  }

  auto gemm = [&](const float* A, int li, const float* bb, float* C, bool relu, bool bias_on) {
    dim3 g((M + 127) / 128, (Nd[li] + 127) / 128);
    if (relu)
      gemm_kernel<true, true><<<g, 256, 0, stream>>>(A, Wt[li], bb, C, M, Kd[li], Kp[li], Nd[li]);
    else if (bias_on)
      gemm_kernel<false, true><<<g, 256, 0, stream>>>(A, Wt[li], bb, C, M, Kd[li], Kp[li], Nd[li]);
    else
      gemm_kernel<false, false><<<g, 256, 0, stream>>>(A, Wt[li], nullptr, C, M, Kd[li], Kp[li], Nd[li]);
  };
  auto spmm = [&](const float* S, const float* bb, float* out, int dim, bool relu, bool bias_on) {
    int nv = dim >> 2;
    int thr = nv < 64 ? 64 : (nv > 256 ? 256 : nv);
    if (relu)
      spmm_kernel<true, true><<<M, thr, 0, stream>>>(S, cnt, ec, ev, bb, out, nv);
    else if (bias_on)
      spmm_kernel<false, true><<<M, thr, 0, stream>>>(S, cnt, ec, ev, bb, out, nv);
    else
      spmm_kernel<false, false><<<M, thr, 0, stream>>>(S, cnt, ec, ev, nullptr, out, nv);
  };

  // encoder: support = H@W, agg = A*support, act = relu(agg + b)
  gemm(x, 0, nullptr, P, false, false);  spmm(P, bia[0], Q, 1024, true,  true);
  gemm(Q, 1, nullptr, P, false, false);  spmm(P, bia[1], Q,  512, true,  true);
  gemm(Q, 2, nullptr, P, false, false);  spmm(P, bia[2], Q,  256, true,  true);
  gemm(Q, 3, nullptr, P, false, false);  spmm(P, bia[3], Z,   16, false, true);   // z (no relu)

  // decoder: agg = A*H first (cheaper dim), then act = relu(agg@W + b)
  spmm(Z, nullptr, P,   16, false, false);  gemm(P, 4, bia[4], Q, true,  true);
  spmm(Q, nullptr, P,  256, false, false);  gemm(P, 5, bia[5], Q, true,  true);
  spmm(Q, nullptr, P,  512, false, false);  gemm(P, 6, bia[6], Q, true,  true);
  spmm(Q, nullptr, P, 1024, false, false);  gemm(P, 7, bia[7], XR, false, true);  // x_recon
}

// Round 2
// 2537.435 us; speedup vs baseline: 1.9076x; 1.9076x over previous
//
#include <hip/hip_runtime.h>

#define CAP 128   // padded-ELL row capacity; max degree ~60 for Poisson(32)

typedef __bf16 bf16x8 __attribute__((ext_vector_type(8)));
typedef float  f32x4  __attribute__((ext_vector_type(4)));

__device__ __forceinline__ unsigned short f2bf(float f) {
  // round-to-nearest-even float -> bf16 (inputs are finite)
  unsigned int u = __float_as_uint(f);
  unsigned int r = (u + 0x7FFFu + ((u >> 16) & 1u)) >> 16;
  return (unsigned short)r;
}

// ---------------- x cast+pad: X[M][K] f32 -> Xb[M][Kp] bf16, zero-padded ----
__global__ __launch_bounds__(256)
void cast_pad_bf16(const float* __restrict__ X, unsigned short* __restrict__ Xb,
                   int M, int K, int Kp) {
  int k = blockIdx.x * 256 + threadIdx.x;
  int r = blockIdx.y;
  if (k >= Kp) return;
  float v = (k < K) ? X[(size_t)r * K + k] : 0.f;
  Xb[(size_t)r * Kp + k] = f2bf(v);
}

// ---------------- weight transpose + cast:  W[K][Nv] f32 -> Wt[Nv][Kp] bf16 (zero-padded K) ----
__global__ __launch_bounds__(256)
void transpose_cast(const float* __restrict__ W, unsigned short* __restrict__ Wt,
                    int K, int Nv, int Kp) {
  __shared__ float tile[32][33];
  int kb = blockIdx.x * 32, nb = blockIdx.y * 32;
  int tx = threadIdx.x, ty = threadIdx.y;   // 32 x 8
  for (int i = ty; i < 32; i += 8) {
    int k = kb + i, n = nb + tx;
    tile[i][tx] = (k < K && n < Nv) ? W[(size_t)k * Nv + n] : 0.f;
  }
  __syncthreads();
  for (int i = ty; i < 32; i += 8) {
    int n = nb + i, k = kb + tx;
    if (n < Nv && k < Kp) Wt[(size_t)n * Kp + k] = f2bf(tile[tx][i]);
  }
}

// ---------------- padded-ELL build ----------------
__global__ __launch_bounds__(256)
void ell_build(const int* __restrict__ erows, const int* __restrict__ ecols,
               const float* __restrict__ evals, int* __restrict__ cnt,
               int* __restrict__ ec, float* __restrict__ ev, int E) {
  int e = blockIdx.x * 256 + threadIdx.x;
  if (e >= E) return;
  int r = erows[e];
  int slot = atomicAdd(&cnt[r], 1);
  if (slot < CAP) {
    ec[(size_t)r * CAP + slot] = ecols[e];
    ev[(size_t)r * CAP + slot] = evals[e];
  }
}

// ---------------- SpMM over padded ELL: out[r][:] = sum_j val_j * S[col_j][:]  (+bias,relu) ----
template<bool RELU, bool BIAS>
__global__ __launch_bounds__(256)
void spmm_kernel(const float* __restrict__ S, const int* __restrict__ cnt,
                 const int* __restrict__ ec, const float* __restrict__ ev,
                 const float* __restrict__ bias, float* __restrict__ out, int nv /*dim/4*/) {
  int r = blockIdx.x;
  int t = threadIdx.x;
  if (t >= nv) return;
  int c = cnt[r]; if (c > CAP) c = CAP;
  const float4* S4 = (const float4*)S;
  float4 acc = make_float4(0.f, 0.f, 0.f, 0.f);
  size_t base = (size_t)r * CAP;
  for (int j = 0; j < c; ++j) {
    int col = ec[base + j];
    float v  = ev[base + j];
    float4 s = S4[(size_t)col * nv + t];
    acc.x += v * s.x; acc.y += v * s.y; acc.z += v * s.z; acc.w += v * s.w;
  }
  if (BIAS) {
    float4 bb = ((const float4*)bias)[t];
    acc.x += bb.x; acc.y += bb.y; acc.z += bb.z; acc.w += bb.w;
  }
  if (RELU) {
    acc.x = fmaxf(acc.x, 0.f); acc.y = fmaxf(acc.y, 0.f);
    acc.z = fmaxf(acc.z, 0.f); acc.w = fmaxf(acc.w, 0.f);
  }
  ((float4*)out)[(size_t)r * nv + t] = acc;
}

// ---------------- GEMM: C[M][Nv] = A[M][K] @ Wt[Nv][Kp]^T ------
// A is f32 (cast to bf16 in staging) or pre-padded bf16 (ABF=true, K==Kp).
// 128x128 tile, BK=32, 4 waves of 64x64 = 4x4 mfma_f32_16x16x32_bf16 fragments.
template<bool RELU, bool BIAS, bool ABF>
__global__ __launch_bounds__(256)
void gemm_kernel(const void* __restrict__ Ap, const unsigned short* __restrict__ Bt,
                 const float* __restrict__ bias, float* __restrict__ C,
                 int M, int K, int Kp, int Nv) {
  __shared__ unsigned short As[128][40];   // +8 pad: bounded bank aliasing on ds_read_b128
  __shared__ unsigned short Bs[128][40];

  int m0 = blockIdx.x * 128, n0 = blockIdx.y * 128;
  int t = threadIdx.x;
  int w = t >> 6, l = t & 63;
  int wr = (w >> 1) * 64, wc = (w & 1) * 64;
  int lr = l & 15, lk = (l >> 4) * 8;

  f32x4 acc[4][4] = {};

  int srow = t >> 1;              // staging: 128 rows, 2 threads/row
  int skg  = (t & 1) * 16;        // each thread stages 16 elements of K

  int nk = (K + 31) / 32;
  for (int kt = 0; kt < nk; ++kt) {
    int k0 = kt * 32;
    { // stage A
      int gm = m0 + srow;
      unsigned short* dst = &As[srow][skg];
      if (ABF) {
        uint4 v0 = make_uint4(0,0,0,0), v1 = make_uint4(0,0,0,0);
        if (gm < M) {
          const uint4* src = reinterpret_cast<const uint4*>(
              (const unsigned short*)Ap + (size_t)gm * Kp + k0 + skg);
          v0 = src[0]; v1 = src[1];
        }
        reinterpret_cast<uint4*>(dst)[0] = v0;
        reinterpret_cast<uint4*>(dst)[1] = v1;
      } else {
        const float* A = (const float*)Ap;
        const float* src = A + (size_t)gm * K + k0 + skg;
        if (gm < M && (K & 3) == 0 && k0 + skg + 16 <= K) {
          #pragma unroll
          for (int j = 0; j < 4; ++j) {
            float4 v = reinterpret_cast<const float4*>(src)[j];
            unsigned int lo = (unsigned int)f2bf(v.x) | ((unsigned int)f2bf(v.y) << 16);
            unsigned int hi = (unsigned int)f2bf(v.z) | ((unsigned int)f2bf(v.w) << 16);
            reinterpret_cast<uint2*>(dst)[j] = make_uint2(lo, hi);
          }
        } else {
          for (int j = 0; j < 16; ++j) {
            int k = k0 + skg + j;
            float v = (gm < M && k < K) ? A[(size_t)gm * K + k] : 0.f;
            dst[j] = f2bf(v);
          }
        }
      }
    }
    { // stage B (bf16 copy from padded Wt)
      int gn = n0 + srow;
      unsigned short* dst = &Bs[srow][skg];
      if (gn < Nv && k0 + skg + 16 <= Kp) {
        const uint4* src = reinterpret_cast<const uint4*>(Bt + (size_t)gn * Kp + k0 + skg);
        reinterpret_cast<uint4*>(dst)[0] = src[0];
        reinterpret_cast<uint4*>(dst)[1] = src[1];
      } else {
        for (int j = 0; j < 16; ++j) {
          int k = k0 + skg + j;
          dst[j] = (gn < Nv && k < Kp) ? Bt[(size_t)gn * Kp + k] : (unsigned short)0;
        }
      }
    }
    __syncthreads();

    bf16x8 a[4], b[4];
    #pragma unroll
    for (int i = 0; i < 4; ++i)
      a[i] = *reinterpret_cast<const bf16x8*>(&As[wr + i * 16 + lr][lk]);
    #pragma unroll
    for (int j = 0; j < 4; ++j)
      b[j] = *reinterpret_cast<const bf16x8*>(&Bs[wc + j * 16 + lr][lk]);
    #pragma unroll
    for (int i = 0; i < 4; ++i)
      #pragma unroll
      for (int j = 0; j < 4; ++j)
        acc[i][j] = __builtin_amdgcn_mfma_f32_16x16x32_bf16(a[i], b[j], acc[i][j], 0, 0, 0);
    __syncthreads();
  }

  // epilogue: C/D layout col=lane&15, row=(lane>>4)*4+reg  [m89-verified]
  int cr = (l >> 4) * 4, cc = l & 15;
  #pragma unroll
  for (int i = 0; i < 4; ++i) {
    #pragma unroll
    for (int j = 0; j < 4; ++j) {
      int gcol = n0 + wc + j * 16 + cc;
      if (gcol >= Nv) continue;
      float bv = BIAS ? bias[gcol] : 0.f;
      #pragma unroll
      for (int q = 0; q < 4; ++q) {
        int grow = m0 + wr + i * 16 + cr + q;
        if (grow >= M) continue;
        float v = acc[i][j][q] + bv;
        if (RELU) v = fmaxf(v, 0.f);
        C[(size_t)grow * Nv + gcol] = v;
      }
    }
  }
}

// ------------------------------------------------------------------------------------
extern "C" void kernel_launch(void* const* d_in, const int* in_sizes, int n_in,
                              void* d_out, int out_size, void* d_ws, size_t ws_size,
                              hipStream_t stream) {
  const float* x        = (const float*)d_in[0];
  const int*   erows    = (const int*)d_in[1];
  const int*   ecols_in = (const int*)d_in[2];
  const float* evals_in = (const float*)d_in[3];
  const float* w[8]; const float* bia[8];
  for (int i = 0; i < 8; ++i) { w[i] = (const float*)d_in[4 + 2 * i]; bia[i] = (const float*)d_in[5 + 2 * i]; }

  const int IN_DIM = 3703;
  const int M = in_sizes[0] / IN_DIM;       // 20000
  const int E = in_sizes[1];                // 640000
  // layer i: GEMM K -> Nv   (0-3 encoder, 4-7 decoder)
  const int Kd[8] = {3703, 1024, 512, 256,   16, 256, 512, 1024};
  const int Nd[8] = {1024,  512, 256,  16,  256, 512, 1024, 3703};
  int Kp[8]; for (int i = 0; i < 8; ++i) Kp[i] = (Kd[i] + 15) & ~15;

  // workspace carve
  char* p = (char*)d_ws;
  auto alloc = [&](size_t bytes) { char* r = p; p += (bytes + 255) & ~(size_t)255; return r; };
  unsigned short* Wt[8];
  for (int i = 0; i < 8; ++i) Wt[i] = (unsigned short*)alloc((size_t)Nd[i] * Kp[i] * 2);
  int*   cnt = (int*)alloc((size_t)M * 4);
  int*   ec  = (int*)alloc((size_t)M * CAP * 4);
  float* ev  = (float*)alloc((size_t)M * CAP * 4);
  float* P   = (float*)alloc((size_t)M * 1024 * 4);

  // optional padded-bf16 copy of x (148 MB) — only if ws has room
  size_t xbf_bytes = (size_t)M * Kp[0] * 2;
  bool useXbf = ((size_t)(p - (char*)d_ws) + xbf_bytes) <= ws_size;
  unsigned short* Xbf = useXbf ? (unsigned short*)alloc(xbf_bytes) : nullptr;

  float* Z  = (float*)d_out;                // z region: M x 16
  float* Q  = (float*)d_out + (size_t)M * 16;  // activation ping buffer aliases x_recon region
  float* XR = Q;                            // x_recon written last, after Q's final read

  // prep: adjacency + weights + x cast
  hipMemsetAsync(cnt, 0, (size_t)M * 4, stream);
  ell_build<<<(E + 255) / 256, 256, 0, stream>>>(erows, ecols_in, evals_in, cnt, ec, ev, E);
  for (int i = 0; i < 8; ++i) {
    dim3 g((Kp[i] + 31) / 32, (Nd[i] + 31) / 32);
    transpose_cast<<<g, dim3(32, 8), 0, stream>>>(w[i], Wt[i], Kd[i], Nd[i], Kp[i]);
  }
  if (useXbf) {
    dim3 g((Kp[0] + 255) / 256, M);
    cast_pad_bf16<<<g, 256, 0, stream>>>(x, Xbf, M, IN_DIM, Kp[0]);
  }

  auto gemm = [&](const void* A, int li, const float* bb, float* C,
                  bool relu, bool bias_on, bool abf) {
    dim3 g((M + 127) / 128, (Nd[li] + 127) / 128);
    int K = abf ? Kp[li] : Kd[li];
    if (abf) {
      if (relu)
        gemm_kernel<true, true, true><<<g, 256, 0, stream>>>(A, Wt[li], bb, C, M, K, Kp[li], Nd[li]);
      else if (bias_on)
        gemm_kernel<false, true, true><<<g, 256, 0, stream>>>(A, Wt[li], bb, C, M, K, Kp[li], Nd[li]);
      else
        gemm_kernel<false, false, true><<<g, 256, 0, stream>>>(A, Wt[li], nullptr, C, M, K, Kp[li], Nd[li]);
    } else {
      if (relu)
        gemm_kernel<true, true, false><<<g, 256, 0, stream>>>(A, Wt[li], bb, C, M, K, Kp[li], Nd[li]);
      else if (bias_on)
        gemm_kernel<false, true, false><<<g, 256, 0, stream>>>(A, Wt[li], bb, C, M, K, Kp[li], Nd[li]);
      else
        gemm_kernel<false, false, false><<<g, 256, 0, stream>>>(A, Wt[li], nullptr, C, M, K, Kp[li], Nd[li]);
    }
  };
  auto spmm = [&](const float* S, const float* bb, float* out, int dim, bool relu, bool bias_on) {
    int nv = dim >> 2;
    int thr = nv < 64 ? 64 : (nv > 256 ? 256 : nv);
    if (relu)
      spmm_kernel<true, true><<<M, thr, 0, stream>>>(S, cnt, ec, ev, bb, out, nv);
    else if (bias_on)
      spmm_kernel<false, true><<<M, thr, 0, stream>>>(S, cnt, ec, ev, bb, out, nv);
    else
      spmm_kernel<false, false><<<M, thr, 0, stream>>>(S, cnt, ec, ev, nullptr, out, nv);
  };

  // encoder: support = H@W, agg = A*support, act = relu(agg + b)
  if (useXbf) gemm(Xbf, 0, nullptr, P, false, false, true);
  else        gemm(x,   0, nullptr, P, false, false, false);
  spmm(P, bia[0], Q, 1024, true,  true);
  gemm(Q, 1, nullptr, P, false, false, false);  spmm(P, bia[1], Q,  512, true,  true);
  gemm(Q, 2, nullptr, P, false, false, false);  spmm(P, bia[2], Q,  256, true,  true);
  gemm(Q, 3, nullptr, P, false, false, false);  spmm(P, bia[3], Z,   16, false, true);   // z (no relu)

  // decoder: agg = A*H first (cheaper dim), then act = relu(agg@W + b)
  spmm(Z, nullptr, P,   16, false, false);  gemm(P, 4, bia[4], Q, true,  true, false);
  spmm(Q, nullptr, P,  256, false, false);  gemm(P, 5, bia[5], Q, true,  true, false);
  spmm(Q, nullptr, P,  512, false, false);  gemm(P, 6, bia[6], Q, true,  true, false);
  spmm(Q, nullptr, P, 1024, false, false);  gemm(P, 7, bia[7], XR, false, true, false);  // x_recon
}

// Round 3
// 2271.096 us; speedup vs baseline: 2.1314x; 1.1173x over previous
//
#include <hip/hip_runtime.h>

#define CAP 128   // padded-ELL row capacity; max degree ~60 for Poisson(32)

typedef __bf16 bf16x8 __attribute__((ext_vector_type(8)));
typedef float  f32x4  __attribute__((ext_vector_type(4)));

__device__ __forceinline__ unsigned short f2bf(float f) {
  unsigned int u = __float_as_uint(f);
  unsigned int r = (u + 0x7FFFu + ((u >> 16) & 1u)) >> 16;
  return (unsigned short)r;
}

__device__ __forceinline__ void gload_lds16(const void* g, void* l) {
  __builtin_amdgcn_global_load_lds(
      (const __attribute__((address_space(1))) unsigned int*)g,
      (__attribute__((address_space(3))) unsigned int*)l, 16, 0, 0);
}

// ---------------- x cast+pad: X[M][K] f32 -> Xb[M][Kp] bf16, zero-padded ----
__global__ __launch_bounds__(256)
void cast_pad_bf16(const float* __restrict__ X, unsigned short* __restrict__ Xb,
                   int M, int K, int Kp) {
  int k = blockIdx.x * 256 + threadIdx.x;
  int r = blockIdx.y;
  if (k >= Kp) return;
  float v = (k < K) ? X[(size_t)r * K + k] : 0.f;
  Xb[(size_t)r * Kp + k] = f2bf(v);
}

// ---------------- weight transpose + cast:  W[K][Nv] f32 -> Wt[Nv][Kp] bf16 (zero-padded K) ----
__global__ __launch_bounds__(256)
void transpose_cast(const float* __restrict__ W, unsigned short* __restrict__ Wt,
                    int K, int Nv, int Kp) {
  __shared__ float tile[32][33];
  int kb = blockIdx.x * 32, nb = blockIdx.y * 32;
  int tx = threadIdx.x, ty = threadIdx.y;   // 32 x 8
  for (int i = ty; i < 32; i += 8) {
    int k = kb + i, n = nb + tx;
    tile[i][tx] = (k < K && n < Nv) ? W[(size_t)k * Nv + n] : 0.f;
  }
  __syncthreads();
  for (int i = ty; i < 32; i += 8) {
    int n = nb + i, k = kb + tx;
    if (n < Nv && k < Kp) Wt[(size_t)n * Kp + k] = f2bf(tile[tx][i]);
  }
}

// ---------------- padded-ELL build ----------------
__global__ __launch_bounds__(256)
void ell_build(const int* __restrict__ erows, const int* __restrict__ ecols,
               const float* __restrict__ evals, int* __restrict__ cnt,
               int* __restrict__ ec, float* __restrict__ ev, int E) {
  int e = blockIdx.x * 256 + threadIdx.x;
  if (e >= E) return;
  int r = erows[e];
  int slot = atomicAdd(&cnt[r], 1);
  if (slot < CAP) {
    ec[(size_t)r * CAP + slot] = ecols[e];
    ev[(size_t)r * CAP + slot] = evals[e];
  }
}

// ---------------- SpMM over padded ELL ----------------
// out[r][:] = sum_j val_j * S[col_j][:]  (+bias, relu); OUTBF: bf16 out, row stride ldo4*4 elems
template<bool RELU, bool BIAS, bool OUTBF>
__global__ __launch_bounds__(256)
void spmm_kernel(const float* __restrict__ S, const int* __restrict__ cnt,
                 const int* __restrict__ ec, const float* __restrict__ ev,
                 const float* __restrict__ bias, void* __restrict__ outp,
                 int nv /*dim/4*/, int ldo4) {
  int r = blockIdx.x;
  int t = threadIdx.x;
  if (t >= nv) {
    if (OUTBF && t < ldo4) {   // zero the K-pad columns for the consuming GEMM
      ushort4 z; z.x = z.y = z.z = z.w = 0;
      ((ushort4*)outp)[(size_t)r * ldo4 + t] = z;
    }
    return;
  }
  int c = cnt[r]; if (c > CAP) c = CAP;
  const float4* S4 = (const float4*)S;
  float4 acc = make_float4(0.f, 0.f, 0.f, 0.f);
  size_t base = (size_t)r * CAP;
  for (int j = 0; j < c; ++j) {
    int col = ec[base + j];
    float v  = ev[base + j];
    float4 s = S4[(size_t)col * nv + t];
    acc.x += v * s.x; acc.y += v * s.y; acc.z += v * s.z; acc.w += v * s.w;
  }
  if (BIAS) {
    float4 bb = ((const float4*)bias)[t];
    acc.x += bb.x; acc.y += bb.y; acc.z += bb.z; acc.w += bb.w;
  }
  if (RELU) {
    acc.x = fmaxf(acc.x, 0.f); acc.y = fmaxf(acc.y, 0.f);
    acc.z = fmaxf(acc.z, 0.f); acc.w = fmaxf(acc.w, 0.f);
  }
  if (OUTBF) {
    ushort4 o;
    o.x = f2bf(acc.x); o.y = f2bf(acc.y); o.z = f2bf(acc.z); o.w = f2bf(acc.w);
    ((ushort4*)outp)[(size_t)r * ldo4 + t] = o;
  } else {
    ((float4*)outp)[(size_t)r * nv + t] = acc;
  }
}

// ---------------- fast GEMM (m97 structure): C[M][Nv] = A[M][K]bf16 @ Bt[Nv][K]bf16^T ----
// 128x128 tile, BK=32, global_load_lds width-16 into linear [128][32] LDS.
// grid: x = n-block (fast), y = m-block  -> concurrent blocks share the A panel.
template<bool RELU, bool BIAS>
__global__ __launch_bounds__(256)
void gemm_bf16(const unsigned short* __restrict__ A, int LDA,
               const unsigned short* __restrict__ Bt, int LDB,
               const float* __restrict__ bias, float* __restrict__ C,
               int M, int Nv, int K) {
  __shared__ unsigned short As[128 * 32];
  __shared__ unsigned short Bs[128 * 32];
  int n0 = blockIdx.x * 128, m0 = blockIdx.y * 128;
  int t = threadIdx.x, w = t >> 6, l = t & 63;
  int wr = (w >> 1) * 64, wc = (w & 1) * 64;
  int lr = l & 15;

  f32x4 acc[4][4] = {};

  // staging: wave w owns rows [w*32, w*32+32); lane l -> row sub l>>2, col elems (l&3)*8
  const unsigned short* ga = A + (size_t)(m0 + w * 32 + (l >> 2)) * LDA + (l & 3) * 8;
  const unsigned short* gb = Bt + (size_t)(n0 + w * 32 + (l >> 2)) * LDB + (l & 3) * 8;
  unsigned short* la0 = &As[(w * 32) * 32];
  unsigned short* la1 = &As[(w * 32 + 16) * 32];
  unsigned short* lb0 = &Bs[(w * 32) * 32];
  unsigned short* lb1 = &Bs[(w * 32 + 16) * 32];

  int nk = K >> 5;
  for (int kt = 0; kt < nk; ++kt) {
    gload_lds16(ga, la0);
    gload_lds16(ga + (size_t)16 * LDA, la1);
    gload_lds16(gb, lb0);
    gload_lds16(gb + (size_t)16 * LDB, lb1);
    ga += 32; gb += 32;
    __syncthreads();

    bf16x8 a[4], b[4];
    const unsigned short* pa = &As[(wr + lr) * 32 + (l >> 4) * 8];
    const unsigned short* pb = &Bs[(wc + lr) * 32 + (l >> 4) * 8];
    #pragma unroll
    for (int i = 0; i < 4; ++i) a[i] = *(const bf16x8*)(pa + i * 16 * 32);
    #pragma unroll
    for (int j = 0; j < 4; ++j) b[j] = *(const bf16x8*)(pb + j * 16 * 32);
    #pragma unroll
    for (int i = 0; i < 4; ++i)
      #pragma unroll
      for (int j = 0; j < 4; ++j)
        acc[i][j] = __builtin_amdgcn_mfma_f32_16x16x32_bf16(a[i], b[j], acc[i][j], 0, 0, 0);
    __syncthreads();
  }

  int cr = (l >> 4) * 4, cc = l & 15;
  #pragma unroll
  for (int i = 0; i < 4; ++i) {
    #pragma unroll
    for (int j = 0; j < 4; ++j) {
      int gcol = n0 + wc + j * 16 + cc;
      if (gcol >= Nv) continue;
      float bv = BIAS ? bias[gcol] : 0.f;
      #pragma unroll
      for (int q = 0; q < 4; ++q) {
        int grow = m0 + wr + i * 16 + cr + q;
        if (grow >= M) continue;
        float v = acc[i][j][q] + bv;
        if (RELU) v = fmaxf(v, 0.f);
        C[(size_t)grow * Nv + gcol] = v;
      }
    }
  }
}

// ---------------- fallback GEMM (register staging, round-1) ----------------
template<bool RELU, bool BIAS, bool ABF>
__global__ __launch_bounds__(256)
void gemm_old(const void* __restrict__ Ap, const unsigned short* __restrict__ Bt,
              const float* __restrict__ bias, float* __restrict__ C,
              int M, int K, int Kp, int Nv) {
  __shared__ unsigned short As[128][40];
  __shared__ unsigned short Bs[128][40];
  int m0 = blockIdx.x * 128, n0 = blockIdx.y * 128;
  int t = threadIdx.x;
  int w = t >> 6, l = t & 63;
  int wr = (w >> 1) * 64, wc = (w & 1) * 64;
  int lr = l & 15, lk = (l >> 4) * 8;
  f32x4 acc[4][4] = {};
  int srow = t >> 1;
  int skg  = (t & 1) * 16;
  int nk = (K + 31) / 32;
  for (int kt = 0; kt < nk; ++kt) {
    int k0 = kt * 32;
    {
      int gm = m0 + srow;
      unsigned short* dst = &As[srow][skg];
      if (ABF) {
        uint4 v0 = make_uint4(0,0,0,0), v1 = make_uint4(0,0,0,0);
        if (gm < M) {
          const uint4* src = reinterpret_cast<const uint4*>(
              (const unsigned short*)Ap + (size_t)gm * Kp + k0 + skg);
          v0 = src[0]; v1 = src[1];
        }
        reinterpret_cast<uint4*>(dst)[0] = v0;
        reinterpret_cast<uint4*>(dst)[1] = v1;
      } else {
        const float* A = (const float*)Ap;
        const float* src = A + (size_t)gm * K + k0 + skg;
        if (gm < M && (K & 3) == 0 && k0 + skg + 16 <= K) {
          #pragma unroll
          for (int j = 0; j < 4; ++j) {
            float4 v = reinterpret_cast<const float4*>(src)[j];
            unsigned int lo = (unsigned int)f2bf(v.x) | ((unsigned int)f2bf(v.y) << 16);
            unsigned int hi = (unsigned int)f2bf(v.z) | ((unsigned int)f2bf(v.w) << 16);
            reinterpret_cast<uint2*>(dst)[j] = make_uint2(lo, hi);
          }
        } else {
          for (int j = 0; j < 16; ++j) {
            int k = k0 + skg + j;
            float v = (gm < M && k < K) ? A[(size_t)gm * K + k] : 0.f;
            dst[j] = f2bf(v);
          }
        }
      }
    }
    {
      int gn = n0 + srow;
      unsigned short* dst = &Bs[srow][skg];
      if (gn < Nv && k0 + skg + 16 <= Kp) {
        const uint4* src = reinterpret_cast<const uint4*>(Bt + (size_t)gn * Kp + k0 + skg);
        reinterpret_cast<uint4*>(dst)[0] = src[0];
        reinterpret_cast<uint4*>(dst)[1] = src[1];
      } else {
        for (int j = 0; j < 16; ++j) {
          int k = k0 + skg + j;
          dst[j] = (gn < Nv && k < Kp) ? Bt[(size_t)gn * Kp + k] : (unsigned short)0;
        }
      }
    }
    __syncthreads();
    bf16x8 a[4], b[4];
    #pragma unroll
    for (int i = 0; i < 4; ++i) a[i] = *reinterpret_cast<const bf16x8*>(&As[wr + i * 16 + lr][lk]);
    #pragma unroll
    for (int j = 0; j < 4; ++j) b[j] = *reinterpret_cast<const bf16x8*>(&Bs[wc + j * 16 + lr][lk]);
    #pragma unroll
    for (int i = 0; i < 4; ++i)
      #pragma unroll
      for (int j = 0; j < 4; ++j)
        acc[i][j] = __builtin_amdgcn_mfma_f32_16x16x32_bf16(a[i], b[j], acc[i][j], 0, 0, 0);
    __syncthreads();
  }
  int cr = (l >> 4) * 4, cc = l & 15;
  #pragma unroll
  for (int i = 0; i < 4; ++i) {
    #pragma unroll
    for (int j = 0; j < 4; ++j) {
      int gcol = n0 + wc + j * 16 + cc;
      if (gcol >= Nv) continue;
      float bv = BIAS ? bias[gcol] : 0.f;
      #pragma unroll
      for (int q = 0; q < 4; ++q) {
        int grow = m0 + wr + i * 16 + cr + q;
        if (grow >= M) continue;
        float v = acc[i][j][q] + bv;
        if (RELU) v = fmaxf(v, 0.f);
        C[(size_t)grow * Nv + gcol] = v;
      }
    }
  }
}

// ------------------------------------------------------------------------------------
extern "C" void kernel_launch(void* const* d_in, const int* in_sizes, int n_in,
                              void* d_out, int out_size, void* d_ws, size_t ws_size,
                              hipStream_t stream) {
  const float* x        = (const float*)d_in[0];
  const int*   erows    = (const int*)d_in[1];
  const int*   ecols_in = (const int*)d_in[2];
  const float* evals_in = (const float*)d_in[3];
  const float* w[8]; const float* bia[8];
  for (int i = 0; i < 8; ++i) { w[i] = (const float*)d_in[4 + 2 * i]; bia[i] = (const float*)d_in[5 + 2 * i]; }

  const int IN_DIM = 3703;
  const int M = in_sizes[0] / IN_DIM;       // 20000
  const int E = in_sizes[1];                // 640000
  const int Kd[8] = {3703, 1024, 512, 256,   16, 256, 512, 1024};
  const int Nd[8] = {1024,  512, 256,  16,  256, 512, 1024, 3703};
  int Kp[8], Nvp[8];
  for (int i = 0; i < 8; ++i) { Kp[i] = (Kd[i] + 31) & ~31; Nvp[i] = (Nd[i] + 127) & ~127; }

  auto al = [](size_t x) { return (x + 255) & ~(size_t)255; };
  size_t wtB[8], wtTot = 0;
  for (int i = 0; i < 8; ++i) { wtB[i] = al((size_t)Nvp[i] * Kp[i] * 2); wtTot += wtB[i]; }
  size_t cntB = al((size_t)M * 4), ecB = al((size_t)M * CAP * 4), evB = ecB;
  size_t xbfB = al((size_t)M * Kp[0] * 2);
  size_t a1B  = al((size_t)M * 1024 * 2);
  size_t pB   = al((size_t)M * 1024 * 4);
  bool fast = (wtTot + cntB + ecB + evB + xbfB + a1B + pB) <= ws_size;

  float* Z  = (float*)d_out;                    // M x 16
  float* XR = (float*)d_out + (size_t)M * 16;   // M x 3703

  if (fast) {
    char* p = (char*)d_ws;
    auto alloc = [&](size_t bytes) { char* r = p; p += al(bytes); return r; };
    unsigned short* Wt[8];
    for (int i = 0; i < 8; ++i) Wt[i] = (unsigned short*)alloc(wtB[i]);
    int*   cnt = (int*)alloc(cntB);
    int*   ec  = (int*)alloc(ecB);
    float* ev  = (float*)alloc(evB);
    unsigned short* Xbf = (unsigned short*)alloc(xbfB);  // OOB tile rows spill into A1 (allocated)
    unsigned short* A1  = (unsigned short*)alloc(a1B);   // OOB tile rows spill into P (allocated)
    float* P   = (float*)alloc(pB);

    hipMemsetAsync(cnt, 0, (size_t)M * 4, stream);
    ell_build<<<(E + 255) / 256, 256, 0, stream>>>(erows, ecols_in, evals_in, cnt, ec, ev, E);
    for (int i = 0; i < 8; ++i) {
      dim3 g((Kp[i] + 31) / 32, (Nd[i] + 31) / 32);
      transpose_cast<<<g, dim3(32, 8), 0, stream>>>(w[i], Wt[i], Kd[i], Nd[i], Kp[i]);
    }
    { dim3 g((Kp[0] + 255) / 256, M);
      cast_pad_bf16<<<g, 256, 0, stream>>>(x, Xbf, M, IN_DIM, Kp[0]); }

    auto gemm = [&](const unsigned short* A, int lda, int li, const float* bb, float* C,
                    bool relu, bool bias_on) {
      dim3 g((Nd[li] + 127) / 128, (M + 127) / 128);   // n fast
      if (relu)
        gemm_bf16<true, true><<<g, 256, 0, stream>>>(A, lda, Wt[li], Kp[li], bb, C, M, Nd[li], Kp[li]);
      else if (bias_on)
        gemm_bf16<false, true><<<g, 256, 0, stream>>>(A, lda, Wt[li], Kp[li], bb, C, M, Nd[li], Kp[li]);
      else
        gemm_bf16<false, false><<<g, 256, 0, stream>>>(A, lda, Wt[li], Kp[li], nullptr, C, M, Nd[li], Kp[li]);
    };
    auto spmmBF = [&](const float* S, const float* bb, unsigned short* out, int dim, int ldo,
                      bool relu, bool bias_on) {
      int nv = dim >> 2, ldo4 = ldo >> 2;
      int thr = nv < 64 ? 64 : (nv > 256 ? 256 : nv);
      if (relu)
        spmm_kernel<true, true, true><<<M, thr, 0, stream>>>(S, cnt, ec, ev, bb, out, nv, ldo4);
      else if (bias_on)
        spmm_kernel<false, true, true><<<M, thr, 0, stream>>>(S, cnt, ec, ev, bb, out, nv, ldo4);
      else
        spmm_kernel<false, false, true><<<M, thr, 0, stream>>>(S, cnt, ec, ev, nullptr, out, nv, ldo4);
    };
    auto spmmF = [&](const float* S, const float* bb, float* out, int dim, bool bias_on) {
      int nv = dim >> 2;
      int thr = nv < 64 ? 64 : (nv > 256 ? 256 : nv);
      if (bias_on)
        spmm_kernel<false, true, false><<<M, thr, 0, stream>>>(S, cnt, ec, ev, bb, out, nv, nv);
      else
        spmm_kernel<false, false, false><<<M, thr, 0, stream>>>(S, cnt, ec, ev, nullptr, out, nv, nv);
    };

    // encoder: support = H@W, agg = A*support (+bias, relu)
    gemm(Xbf, Kp[0], 0, nullptr, P, false, false);
    spmmBF(P, bia[0], A1, 1024, Kp[1], true, true);
    gemm(A1, Kp[1], 1, nullptr, P, false, false);
    spmmBF(P, bia[1], A1, 512, Kp[2], true, true);
    gemm(A1, Kp[2], 2, nullptr, P, false, false);
    spmmBF(P, bia[2], A1, 256, Kp[3], true, true);
    gemm(A1, Kp[3], 3, nullptr, P, false, false);
    spmmF(P, bia[3], Z, 16, true);                    // z (no relu)

    // decoder: agg first (cheap dim), then gemm(+bias,relu)
    spmmBF(Z, nullptr, A1, 16, Kp[4], false, false);
    gemm(A1, Kp[4], 4, bia[4], P, true, true);
    spmmBF(P, nullptr, A1, 256, Kp[5], false, false);
    gemm(A1, Kp[5], 5, bia[5], P, true, true);
    spmmBF(P, nullptr, A1, 512, Kp[6], false, false);
    gemm(A1, Kp[6], 6, bia[6], P, true, true);
    spmmBF(P, nullptr, A1, 1024, Kp[7], false, false);
    gemm(A1, Kp[7], 7, bia[7], XR, false, true);      // x_recon
    return;
  }

  // ---------------- fallback: round-1 path ----------------
  char* p = (char*)d_ws;
  auto alloc = [&](size_t bytes) { char* r = p; p += al(bytes); return r; };
  unsigned short* Wt[8];
  for (int i = 0; i < 8; ++i) Wt[i] = (unsigned short*)alloc((size_t)Nd[i] * Kp[i] * 2);
  int*   cnt = (int*)alloc((size_t)M * 4);
  int*   ec  = (int*)alloc((size_t)M * CAP * 4);
  float* ev  = (float*)alloc((size_t)M * CAP * 4);
  float* P   = (float*)alloc((size_t)M * 1024 * 4);
  size_t xbf_bytes = (size_t)M * Kp[0] * 2;
  bool useXbf = ((size_t)(p - (char*)d_ws) + xbf_bytes) <= ws_size;
  unsigned short* Xbf = useXbf ? (unsigned short*)alloc(xbf_bytes) : nullptr;
  float* Q = (float*)d_out + (size_t)M * 16;

  hipMemsetAsync(cnt, 0, (size_t)M * 4, stream);
  ell_build<<<(E + 255) / 256, 256, 0, stream>>>(erows, ecols_in, evals_in, cnt, ec, ev, E);
  for (int i = 0; i < 8; ++i) {
    dim3 g((Kp[i] + 31) / 32, (Nd[i] + 31) / 32);
    transpose_cast<<<g, dim3(32, 8), 0, stream>>>(w[i], Wt[i], Kd[i], Nd[i], Kp[i]);
  }
  if (useXbf) {
    dim3 g((Kp[0] + 255) / 256, M);
    cast_pad_bf16<<<g, 256, 0, stream>>>(x, Xbf, M, IN_DIM, Kp[0]);
  }
  auto gemm = [&](const void* A, int li, const float* bb, float* C,
                  bool relu, bool bias_on, bool abf) {
    dim3 g((M + 127) / 128, (Nd[li] + 127) / 128);
    int K = abf ? Kp[li] : Kd[li];
    if (abf) {
      if (relu)      gemm_old<true, true, true><<<g, 256, 0, stream>>>(A, Wt[li], bb, C, M, K, Kp[li], Nd[li]);
      else if (bias_on) gemm_old<false, true, true><<<g, 256, 0, stream>>>(A, Wt[li], bb, C, M, K, Kp[li], Nd[li]);
      else           gemm_old<false, false, true><<<g, 256, 0, stream>>>(A, Wt[li], nullptr, C, M, K, Kp[li], Nd[li]);
    } else {
      if (relu)      gemm_old<true, true, false><<<g, 256, 0, stream>>>(A, Wt[li], bb, C, M, K, Kp[li], Nd[li]);
      else if (bias_on) gemm_old<false, true, false><<<g, 256, 0, stream>>>(A, Wt[li], bb, C, M, K, Kp[li], Nd[li]);
      else           gemm_old<false, false, false><<<g, 256, 0, stream>>>(A, Wt[li], nullptr, C, M, K, Kp[li], Nd[li]);
    }
  };
  auto spmm = [&](const float* S, const float* bb, float* out, int dim, bool relu, bool bias_on) {
    int nv = dim >> 2;
    int thr = nv < 64 ? 64 : (nv > 256 ? 256 : nv);
    if (relu)      spmm_kernel<true, true, false><<<M, thr, 0, stream>>>(S, cnt, ec, ev, bb, out, nv, nv);
    else if (bias_on) spmm_kernel<false, true, false><<<M, thr, 0, stream>>>(S, cnt, ec, ev, bb, out, nv, nv);
    else           spmm_kernel<false, false, false><<<M, thr, 0, stream>>>(S, cnt, ec, ev, nullptr, out, nv, nv);
  };

  if (useXbf) gemm(Xbf, 0, nullptr, P, false, false, true);
  else        gemm(x,   0, nullptr, P, false, false, false);
  spmm(P, bia[0], Q, 1024, true,  true);
  gemm(Q, 1, nullptr, P, false, false, false);  spmm(P, bia[1], Q,  512, true,  true);
  gemm(Q, 2, nullptr, P, false, false, false);  spmm(P, bia[2], Q,  256, true,  true);
  gemm(Q, 3, nullptr, P, false, false, false);  spmm(P, bia[3], Z,   16, false, true);
  spmm(Z, nullptr, P,   16, false, false);  gemm(P, 4, bia[4], Q, true,  true, false);
  spmm(Q, nullptr, P,  256, false, false);  gemm(P, 5, bia[5], Q, true,  true, false);
  spmm(Q, nullptr, P,  512, false, false);  gemm(P, 6, bia[6], Q, true,  true, false);
  spmm(Q, nullptr, P, 1024, false, false);  gemm(P, 7, bia[7], XR, false, true, false);
}

// Round 4
// 1539.127 us; speedup vs baseline: 3.1450x; 1.4756x over previous
//
#include <hip/hip_runtime.h>

#define CAP 128   // padded-ELL row capacity; max degree ~60 for Poisson(32)

typedef __bf16 bf16x8 __attribute__((ext_vector_type(8)));
typedef float  f32x4  __attribute__((ext_vector_type(4)));

__device__ __forceinline__ unsigned short f2bf(float f) {
  unsigned int u = __float_as_uint(f);
  unsigned int r = (u + 0x7FFFu + ((u >> 16) & 1u)) >> 16;
  return (unsigned short)r;
}
__device__ __forceinline__ float bf2f(unsigned short u) {
  return __uint_as_float(((unsigned int)u) << 16);
}
__device__ __forceinline__ void gload_lds16(const void* g, void* l) {
  __builtin_amdgcn_global_load_lds(
      (const __attribute__((address_space(1))) unsigned int*)g,
      (__attribute__((address_space(3))) unsigned int*)l, 16, 0, 0);
}

// ---------------- x cast+pad: X[M][K] f32 -> Xb[M][Kp] bf16, zero-padded ----
__global__ __launch_bounds__(256)
void cast_pad_bf16(const float* __restrict__ X, unsigned short* __restrict__ Xb,
                   int M, int K, int Kp) {
  int k = blockIdx.x * 256 + threadIdx.x;
  int r = blockIdx.y;
  if (k >= Kp) return;
  float v = (k < K) ? X[(size_t)r * K + k] : 0.f;
  Xb[(size_t)r * Kp + k] = f2bf(v);
}

// ---------------- weight transpose + cast:  W[K][Nv] f32 -> Wt[Nv][Kp] bf16 ----
__global__ __launch_bounds__(256)
void transpose_cast(const float* __restrict__ W, unsigned short* __restrict__ Wt,
                    int K, int Nv, int Kp) {
  __shared__ float tile[32][33];
  int kb = blockIdx.x * 32, nb = blockIdx.y * 32;
  int tx = threadIdx.x, ty = threadIdx.y;   // 32 x 8
  for (int i = ty; i < 32; i += 8) {
    int k = kb + i, n = nb + tx;
    tile[i][tx] = (k < K && n < Nv) ? W[(size_t)k * Nv + n] : 0.f;
  }
  __syncthreads();
  for (int i = ty; i < 32; i += 8) {
    int n = nb + i, k = kb + tx;
    if (n < Nv && k < Kp) Wt[(size_t)n * Kp + k] = f2bf(tile[tx][i]);
  }
}

// ---------------- padded-ELL build (packed col+val) ----------------
__global__ __launch_bounds__(256)
void ell_build(const int* __restrict__ erows, const int* __restrict__ ecols,
               const float* __restrict__ evals, int* __restrict__ cnt,
               int2* __restrict__ ecv, int E) {
  int e = blockIdx.x * 256 + threadIdx.x;
  if (e >= E) return;
  int r = erows[e];
  int slot = atomicAdd(&cnt[r], 1);
  if (slot < CAP)
    ecv[(size_t)r * CAP + slot] = make_int2(ecols[e], __float_as_int(evals[e]));
}

// ---------------- SpMM, bf16 gather: out[r] = sum val_j * S[col_j]  (+bias, relu) ----
template<bool RELU, bool BIAS, bool OUTBF>
__global__ __launch_bounds__(256)
void spmm_b(const unsigned short* __restrict__ S, const int* __restrict__ cnt,
            const int2* __restrict__ ecv, const float* __restrict__ bias,
            void* __restrict__ outp, int nv /*dim/4*/, int ldo4) {
  __shared__ int2 eb[CAP];
  int r = blockIdx.x, t = threadIdx.x, nt = blockDim.x;
  int c = cnt[r]; if (c > CAP) c = CAP;
  for (int j = t; j < c; j += nt) eb[j] = ecv[(size_t)r * CAP + j];
  __syncthreads();
  if (t >= nv) {
    if (OUTBF && t < ldo4) {  // zero K-pad columns for the consuming GEMM
      ushort4 z; z.x = z.y = z.z = z.w = 0;
      ((ushort4*)outp)[(size_t)r * ldo4 + t] = z;
    }
    return;
  }
  const ushort4* S4 = (const ushort4*)S;
  float ax = 0.f, ay = 0.f, az = 0.f, aw = 0.f;
  for (int j = 0; j < c; ++j) {
    int col = eb[j].x; float v = __int_as_float(eb[j].y);
    ushort4 s = S4[(size_t)col * nv + t];
    ax += v * bf2f(s.x); ay += v * bf2f(s.y); az += v * bf2f(s.z); aw += v * bf2f(s.w);
  }
  if (BIAS) {
    float4 bb = ((const float4*)bias)[t];
    ax += bb.x; ay += bb.y; az += bb.z; aw += bb.w;
  }
  if (RELU) { ax = fmaxf(ax, 0.f); ay = fmaxf(ay, 0.f); az = fmaxf(az, 0.f); aw = fmaxf(aw, 0.f); }
  if (OUTBF) {
    ushort4 o; o.x = f2bf(ax); o.y = f2bf(ay); o.z = f2bf(az); o.w = f2bf(aw);
    ((ushort4*)outp)[(size_t)r * ldo4 + t] = o;
  } else {
    ((float4*)outp)[(size_t)r * nv + t] = make_float4(ax, ay, az, aw);
  }
}

// ---------------- SpMM, f32 gather ----------------
template<bool RELU, bool BIAS, bool OUTBF>
__global__ __launch_bounds__(256)
void spmm_f(const float* __restrict__ S, const int* __restrict__ cnt,
            const int2* __restrict__ ecv, const float* __restrict__ bias,
            void* __restrict__ outp, int nv, int ldo4) {
  __shared__ int2 eb[CAP];
  int r = blockIdx.x, t = threadIdx.x, nt = blockDim.x;
  int c = cnt[r]; if (c > CAP) c = CAP;
  for (int j = t; j < c; j += nt) eb[j] = ecv[(size_t)r * CAP + j];
  __syncthreads();
  if (t >= nv) {
    if (OUTBF && t < ldo4) {
      ushort4 z; z.x = z.y = z.z = z.w = 0;
      ((ushort4*)outp)[(size_t)r * ldo4 + t] = z;
    }
    return;
  }
  const float4* S4 = (const float4*)S;
  float ax = 0.f, ay = 0.f, az = 0.f, aw = 0.f;
  for (int j = 0; j < c; ++j) {
    int col = eb[j].x; float v = __int_as_float(eb[j].y);
    float4 s = S4[(size_t)col * nv + t];
    ax += v * s.x; ay += v * s.y; az += v * s.z; aw += v * s.w;
  }
  if (BIAS) {
    float4 bb = ((const float4*)bias)[t];
    ax += bb.x; ay += bb.y; az += bb.z; aw += bb.w;
  }
  if (RELU) { ax = fmaxf(ax, 0.f); ay = fmaxf(ay, 0.f); az = fmaxf(az, 0.f); aw = fmaxf(aw, 0.f); }
  if (OUTBF) {
    ushort4 o; o.x = f2bf(ax); o.y = f2bf(ay); o.z = f2bf(az); o.w = f2bf(aw);
    ((ushort4*)outp)[(size_t)r * ldo4 + t] = o;
  } else {
    ((float4*)outp)[(size_t)r * nv + t] = make_float4(ax, ay, az, aw);
  }
}

// ---------------- fast GEMM (m97 structure): C[M][Nv] = A[M][K]bf16 @ Bt[Nv][K]bf16^T ----
template<bool RELU, bool BIAS, bool OUTBF>
__global__ __launch_bounds__(256)
void gemm_bf16(const unsigned short* __restrict__ A, int LDA,
               const unsigned short* __restrict__ Bt, int LDB,
               const float* __restrict__ bias, void* __restrict__ Cp, int LDC,
               int M, int Nv, int K) {
  __shared__ unsigned short As[128 * 32];
  __shared__ unsigned short Bs[128 * 32];
  int n0 = blockIdx.x * 128, m0 = blockIdx.y * 128;
  int t = threadIdx.x, w = t >> 6, l = t & 63;
  int wr = (w >> 1) * 64, wc = (w & 1) * 64;
  int lr = l & 15;

  f32x4 acc[4][4] = {};

  const unsigned short* ga = A + (size_t)(m0 + w * 32 + (l >> 2)) * LDA + (l & 3) * 8;
  const unsigned short* gb = Bt + (size_t)(n0 + w * 32 + (l >> 2)) * LDB + (l & 3) * 8;
  unsigned short* la0 = &As[(w * 32) * 32];
  unsigned short* la1 = &As[(w * 32 + 16) * 32];
  unsigned short* lb0 = &Bs[(w * 32) * 32];
  unsigned short* lb1 = &Bs[(w * 32 + 16) * 32];

  int nk = K >> 5;
  for (int kt = 0; kt < nk; ++kt) {
    gload_lds16(ga, la0);
    gload_lds16(ga + (size_t)16 * LDA, la1);
    gload_lds16(gb, lb0);
    gload_lds16(gb + (size_t)16 * LDB, lb1);
    ga += 32; gb += 32;
    __syncthreads();

    bf16x8 a[4], b[4];
    const unsigned short* pa = &As[(wr + lr) * 32 + (l >> 4) * 8];
    const unsigned short* pb = &Bs[(wc + lr) * 32 + (l >> 4) * 8];
    #pragma unroll
    for (int i = 0; i < 4; ++i) a[i] = *(const bf16x8*)(pa + i * 16 * 32);
    #pragma unroll
    for (int j = 0; j < 4; ++j) b[j] = *(const bf16x8*)(pb + j * 16 * 32);
    #pragma unroll
    for (int i = 0; i < 4; ++i)
      #pragma unroll
      for (int j = 0; j < 4; ++j)
        acc[i][j] = __builtin_amdgcn_mfma_f32_16x16x32_bf16(a[i], b[j], acc[i][j], 0, 0, 0);
    __syncthreads();
  }

  int cr = (l >> 4) * 4, cc = l & 15;
  #pragma unroll
  for (int i = 0; i < 4; ++i) {
    #pragma unroll
    for (int j = 0; j < 4; ++j) {
      int gcol = n0 + wc + j * 16 + cc;
      if (gcol >= Nv) continue;
      float bv = BIAS ? bias[gcol] : 0.f;
      #pragma unroll
      for (int q = 0; q < 4; ++q) {
        int grow = m0 + wr + i * 16 + cr + q;
        if (grow >= M) continue;
        float v = acc[i][j][q] + bv;
        if (RELU) v = fmaxf(v, 0.f);
        if (OUTBF) ((unsigned short*)Cp)[(size_t)grow * LDC + gcol] = f2bf(v);
        else       ((float*)Cp)[(size_t)grow * LDC + gcol] = v;
      }
    }
  }
}

// ---------------- fallback GEMM (register staging) ----------------
template<bool RELU, bool BIAS, bool ABF>
__global__ __launch_bounds__(256)
void gemm_old(const void* __restrict__ Ap, const unsigned short* __restrict__ Bt,
              const float* __restrict__ bias, float* __restrict__ C,
              int M, int K, int Kp, int Nv) {
  __shared__ unsigned short As[128][40];
  __shared__ unsigned short Bs[128][40];
  int m0 = blockIdx.x * 128, n0 = blockIdx.y * 128;
  int t = threadIdx.x;
  int w = t >> 6, l = t & 63;
  int wr = (w >> 1) * 64, wc = (w & 1) * 64;
  int lr = l & 15, lk = (l >> 4) * 8;
  f32x4 acc[4][4] = {};
  int srow = t >> 1;
  int skg  = (t & 1) * 16;
  int nk = (K + 31) / 32;
  for (int kt = 0; kt < nk; ++kt) {
    int k0 = kt * 32;
    {
      int gm = m0 + srow;
      unsigned short* dst = &As[srow][skg];
      if (ABF) {
        uint4 v0 = make_uint4(0,0,0,0), v1 = make_uint4(0,0,0,0);
        if (gm < M) {
          const uint4* src = reinterpret_cast<const uint4*>(
              (const unsigned short*)Ap + (size_t)gm * Kp + k0 + skg);
          v0 = src[0]; v1 = src[1];
        }
        reinterpret_cast<uint4*>(dst)[0] = v0;
        reinterpret_cast<uint4*>(dst)[1] = v1;
      } else {
        const float* A = (const float*)Ap;
        const float* src = A + (size_t)gm * K + k0 + skg;
        if (gm < M && (K & 3) == 0 && k0 + skg + 16 <= K) {
          #pragma unroll
          for (int j = 0; j < 4; ++j) {
            float4 v = reinterpret_cast<const float4*>(src)[j];
            unsigned int lo = (unsigned int)f2bf(v.x) | ((unsigned int)f2bf(v.y) << 16);
            unsigned int hi = (unsigned int)f2bf(v.z) | ((unsigned int)f2bf(v.w) << 16);
            reinterpret_cast<uint2*>(dst)[j] = make_uint2(lo, hi);
          }
        } else {
          for (int j = 0; j < 16; ++j) {
            int k = k0 + skg + j;
            float v = (gm < M && k < K) ? A[(size_t)gm * K + k] : 0.f;
            dst[j] = f2bf(v);
          }
        }
      }
    }
    {
      int gn = n0 + srow;
      unsigned short* dst = &Bs[srow][skg];
      if (gn < Nv && k0 + skg + 16 <= Kp) {
        const uint4* src = reinterpret_cast<const uint4*>(Bt + (size_t)gn * Kp + k0 + skg);
        reinterpret_cast<uint4*>(dst)[0] = src[0];
        reinterpret_cast<uint4*>(dst)[1] = src[1];
      } else {
        for (int j = 0; j < 16; ++j) {
          int k = k0 + skg + j;
          dst[j] = (gn < Nv && k < Kp) ? Bt[(size_t)gn * Kp + k] : (unsigned short)0;
        }
      }
    }
    __syncthreads();
    bf16x8 a[4], b[4];
    #pragma unroll
    for (int i = 0; i < 4; ++i) a[i] = *reinterpret_cast<const bf16x8*>(&As[wr + i * 16 + lr][lk]);
    #pragma unroll
    for (int j = 0; j < 4; ++j) b[j] = *reinterpret_cast<const bf16x8*>(&Bs[wc + j * 16 + lr][lk]);
    #pragma unroll
    for (int i = 0; i < 4; ++i)
      #pragma unroll
      for (int j = 0; j < 4; ++j)
        acc[i][j] = __builtin_amdgcn_mfma_f32_16x16x32_bf16(a[i], b[j], acc[i][j], 0, 0, 0);
    __syncthreads();
  }
  int cr = (l >> 4) * 4, cc = l & 15;
  #pragma unroll
  for (int i = 0; i < 4; ++i) {
    #pragma unroll
    for (int j = 0; j < 4; ++j) {
      int gcol = n0 + wc + j * 16 + cc;
      if (gcol >= Nv) continue;
      float bv = BIAS ? bias[gcol] : 0.f;
      #pragma unroll
      for (int q = 0; q < 4; ++q) {
        int grow = m0 + wr + i * 16 + cr + q;
        if (grow >= M) continue;
        float v = acc[i][j][q] + bv;
        if (RELU) v = fmaxf(v, 0.f);
        C[(size_t)grow * Nv + gcol] = v;
      }
    }
  }
}

// ------------------------------------------------------------------------------------
extern "C" void kernel_launch(void* const* d_in, const int* in_sizes, int n_in,
                              void* d_out, int out_size, void* d_ws, size_t ws_size,
                              hipStream_t stream) {
  const float* x        = (const float*)d_in[0];
  const int*   erows    = (const int*)d_in[1];
  const int*   ecols_in = (const int*)d_in[2];
  const float* evals_in = (const float*)d_in[3];
  const float* w[8]; const float* bia[8];
  for (int i = 0; i < 8; ++i) { w[i] = (const float*)d_in[4 + 2 * i]; bia[i] = (const float*)d_in[5 + 2 * i]; }

  const int IN_DIM = 3703;
  const int M = in_sizes[0] / IN_DIM;       // 20000
  const int E = in_sizes[1];                // 640000
  const int Kd[8] = {3703, 1024, 512, 256,   16, 256, 512, 1024};
  const int Nd[8] = {1024,  512, 256,  16,  256, 512, 1024, 3703};
  int Kp[8], Nvp[8];
  for (int i = 0; i < 8; ++i) { Kp[i] = (Kd[i] + 31) & ~31; Nvp[i] = (Nd[i] + 127) & ~127; }

  auto al = [](size_t v) { return (v + 255) & ~(size_t)255; };
  size_t wtB[8], wtTot = 0;
  for (int i = 0; i < 8; ++i) { wtB[i] = al((size_t)Nvp[i] * Kp[i] * 2); wtTot += wtB[i]; }
  size_t cntB = al((size_t)M * 4), ecvB = al((size_t)M * CAP * 8);
  size_t xbfB = al((size_t)M * Kp[0] * 2);
  size_t a1B  = al((size_t)M * 1024 * 2);
  size_t pbB  = al((size_t)M * 1024 * 2);
  size_t grdB = 1 << 20;
  bool fast = (wtTot + cntB + ecvB + xbfB + a1B + pbB + grdB) <= ws_size;

  float* Z  = (float*)d_out;                    // M x 16
  float* XR = (float*)d_out + (size_t)M * 16;   // M x 3703

  if (fast) {
    char* p = (char*)d_ws;
    auto alloc = [&](size_t bytes) { char* r = p; p += al(bytes); return r; };
    unsigned short* Wt[8];
    for (int i = 0; i < 8; ++i) Wt[i] = (unsigned short*)alloc(wtB[i]);
    int*  cnt = (int*)alloc(cntB);
    int2* ecv = (int2*)alloc(ecvB);
    unsigned short* Xbf = (unsigned short*)alloc(xbfB);
    unsigned short* A1  = (unsigned short*)alloc(a1B);
    unsigned short* Pb  = (unsigned short*)alloc(pbB);
    alloc(grdB);   // guard for m-tail OOB staging reads

    hipMemsetAsync(cnt, 0, (size_t)M * 4, stream);
    ell_build<<<(E + 255) / 256, 256, 0, stream>>>(erows, ecols_in, evals_in, cnt, ecv, E);
    for (int i = 0; i < 8; ++i) {
      dim3 g((Kp[i] + 31) / 32, (Nd[i] + 31) / 32);
      transpose_cast<<<g, dim3(32, 8), 0, stream>>>(w[i], Wt[i], Kd[i], Nd[i], Kp[i]);
    }
    { dim3 g((Kp[0] + 255) / 256, M);
      cast_pad_bf16<<<g, 256, 0, stream>>>(x, Xbf, M, IN_DIM, Kp[0]); }

    dim3 gm;  // helper grids
    auto gemmB = [&](const unsigned short* A, int lda, int li, const float* bb,
                     void* C, int ldc, bool relu_bias, bool outbf) {
      dim3 g((Nd[li] + 127) / 128, (M + 127) / 128);   // n fast: panel sharing
      if (outbf) {
        if (relu_bias)
          gemm_bf16<true, true, true><<<g, 256, 0, stream>>>(A, lda, Wt[li], Kp[li], bb, C, ldc, M, Nd[li], Kp[li]);
        else
          gemm_bf16<false, false, true><<<g, 256, 0, stream>>>(A, lda, Wt[li], Kp[li], nullptr, C, ldc, M, Nd[li], Kp[li]);
      } else {
        gemm_bf16<false, true, false><<<g, 256, 0, stream>>>(A, lda, Wt[li], Kp[li], bb, C, ldc, M, Nd[li], Kp[li]);
      }
    };
    auto thrFor = [](int nv, int ldo4) {
      int t = nv > ldo4 ? nv : ldo4; t = (t + 63) & ~63; return t > 256 ? 256 : t;
    };
    // bf16-gather spmm
    auto spmmB = [&](const unsigned short* S, const float* bb, void* out,
                     int dim, int ldo4, bool relu, bool bias_on, bool outbf) {
      int nv = dim >> 2;
      int thr = thrFor(nv, outbf ? ldo4 : nv);
      if (outbf) {
        if (relu) spmm_b<true, true, true><<<M, thr, 0, stream>>>(S, cnt, ecv, bb, out, nv, ldo4);
        else      spmm_b<false, false, true><<<M, thr, 0, stream>>>(S, cnt, ecv, nullptr, out, nv, ldo4);
      } else {
        spmm_b<false, true, false><<<M, thr, 0, stream>>>(S, cnt, ecv, bb, out, nv, nv);
      }
    };

    // ---- encoder: support = H@W (bf16 out), agg = A*support (+bias, relu, bf16) ----
    gemmB(Xbf, Kp[0], 0, nullptr, Pb, 1024, false, true);
    spmmB(Pb, bia[0], A1, 1024, 256, true, true, true);
    gemmB(A1, 1024, 1, nullptr, Pb, 512, false, true);
    spmmB(Pb, bia[1], A1, 512, 128, true, true, true);
    gemmB(A1, 512, 2, nullptr, Pb, 256, false, true);
    spmmB(Pb, bia[2], A1, 256, 64, true, true, true);
    gemmB(A1, 256, 3, nullptr, Pb, 16, false, true);
    spmmB(Pb, bia[3], Z, 16, 4, false, true, false);          // z, f32 out, no relu

    // ---- decoder: agg first (cheap dim), then gemm(+bias,relu,bf16 out) ----
    spmm_f<false, false, true><<<M, 64, 0, stream>>>(Z, cnt, ecv, nullptr, A1, 4, 8); // Z f32 -> A1 bf16 [M][32]
    gemmB(A1, 32, 4, bia[4], Pb, 256, true, true);
    spmmB(Pb, nullptr, A1, 256, 64, false, false, true);
    gemmB(A1, 256, 5, bia[5], Pb, 512, true, true);
    spmmB(Pb, nullptr, A1, 512, 128, false, false, true);
    gemmB(A1, 512, 6, bia[6], Pb, 1024, true, true);
    spmmB(Pb, nullptr, A1, 1024, 256, false, false, true);
    gemmB(A1, 1024, 7, bia[7], XR, 3703, false, false);       // x_recon, f32 out (+bias)
    return;
  }

  // ---------------- fallback: f32 activations, register-staged GEMM ----------------
  char* p = (char*)d_ws;
  auto alloc = [&](size_t bytes) { char* r = p; p += al(bytes); return r; };
  unsigned short* Wt[8];
  for (int i = 0; i < 8; ++i) Wt[i] = (unsigned short*)alloc((size_t)Nd[i] * Kp[i] * 2);
  int*  cnt = (int*)alloc(cntB);
  int2* ecv = (int2*)alloc(ecvB);
  float* P  = (float*)alloc((size_t)M * 1024 * 4);
  size_t used = (size_t)(p - (char*)d_ws);
  bool useXbf = (used + xbfB) <= ws_size;
  unsigned short* Xbf = useXbf ? (unsigned short*)alloc(xbfB) : nullptr;
  float* Q = (float*)d_out + (size_t)M * 16;

  hipMemsetAsync(cnt, 0, (size_t)M * 4, stream);
  ell_build<<<(E + 255) / 256, 256, 0, stream>>>(erows, ecols_in, evals_in, cnt, ecv, E);
  for (int i = 0; i < 8; ++i) {
    dim3 g((Kp[i] + 31) / 32, (Nd[i] + 31) / 32);
    transpose_cast<<<g, dim3(32, 8), 0, stream>>>(w[i], Wt[i], Kd[i], Nd[i], Kp[i]);
  }
  if (useXbf) {
    dim3 g((Kp[0] + 255) / 256, M);
    cast_pad_bf16<<<g, 256, 0, stream>>>(x, Xbf, M, IN_DIM, Kp[0]);
  }
  auto gemm = [&](const void* A, int li, const float* bb, float* C,
                  bool relu, bool bias_on, bool abf) {
    dim3 g((M + 127) / 128, (Nd[li] + 127) / 128);
    int K = abf ? Kp[li] : Kd[li];
    if (abf) {
      if (relu)         gemm_old<true, true, true><<<g, 256, 0, stream>>>(A, Wt[li], bb, C, M, K, Kp[li], Nd[li]);
      else if (bias_on) gemm_old<false, true, true><<<g, 256, 0, stream>>>(A, Wt[li], bb, C, M, K, Kp[li], Nd[li]);
      else              gemm_old<false, false, true><<<g, 256, 0, stream>>>(A, Wt[li], nullptr, C, M, K, Kp[li], Nd[li]);
    } else {
      if (relu)         gemm_old<true, true, false><<<g, 256, 0, stream>>>(A, Wt[li], bb, C, M, K, Kp[li], Nd[li]);
      else if (bias_on) gemm_old<false, true, false><<<g, 256, 0, stream>>>(A, Wt[li], bb, C, M, K, Kp[li], Nd[li]);
      else              gemm_old<false, false, false><<<g, 256, 0, stream>>>(A, Wt[li], nullptr, C, M, K, Kp[li], Nd[li]);
    }
  };
  auto spmm = [&](const float* S, const float* bb, float* out, int dim, bool relu, bool bias_on) {
    int nv = dim >> 2;
    int thr = nv < 64 ? 64 : (nv > 256 ? 256 : nv);
    if (relu)         spmm_f<true, true, false><<<M, thr, 0, stream>>>(S, cnt, ecv, bb, out, nv, nv);
    else if (bias_on) spmm_f<false, true, false><<<M, thr, 0, stream>>>(S, cnt, ecv, bb, out, nv, nv);
    else              spmm_f<false, false, false><<<M, thr, 0, stream>>>(S, cnt, ecv, nullptr, out, nv, nv);
  };

  if (useXbf) gemm(Xbf, 0, nullptr, P, false, false, true);
  else        gemm(x,   0, nullptr, P, false, false, false);
  spmm(P, bia[0], Q, 1024, true,  true);
  gemm(Q, 1, nullptr, P, false, false, false);  spmm(P, bia[1], Q,  512, true,  true);
  gemm(Q, 2, nullptr, P, false, false, false);  spmm(P, bia[2], Q,  256, true,  true);
  gemm(Q, 3, nullptr, P, false, false, false);  spmm(P, bia[3], Z,   16, false, true);
  spmm(Z, nullptr, P,   16, false, false);  gemm(P, 4, bia[4], Q, true,  true, false);
  spmm(Q, nullptr, P,  256, false, false);  gemm(P, 5, bia[5], Q, true,  true, false);
  spmm(Q, nullptr, P,  512, false, false);  gemm(P, 6, bia[6], Q, true,  true, false);
  spmm(Q, nullptr, P, 1024, false, false);  gemm(P, 7, bia[7], XR, false, true, false);
}